// Round 3
// baseline (1252.382 us; speedup 1.0000x reference)
//
#include <hip/hip_runtime.h>

static constexpr float NEG_SLOPE = 0.2f;
#define BUCKET_BITS 7
#define BNODES (1 << BUCKET_BITS)      // 128 nodes per bucket
#define MAXNB 1024                     // supports n <= 131072 (src fits 17 bits)
#define PART_CHUNK 16384

// ---------------- Layer-1 node transform: xl1 = x@W1, a_src/a_dst ----------
__global__ void k_node1(const float* __restrict__ x,
                        const float* __restrict__ w1,    // [3,32]
                        const float* __restrict__ atts,  // [2,16]
                        const float* __restrict__ attd,  // [2,16]
                        float* __restrict__ xl,          // [N,32]
                        float* __restrict__ as_,         // [N,2]
                        float* __restrict__ ad_,         // [N,2]
                        int n) {
  int i = blockIdx.x * blockDim.x + threadIdx.x;
  if (i >= n) return;
  float x0 = x[3*i], x1 = x[3*i+1], x2 = x[3*i+2];
  float v[32];
#pragma unroll
  for (int j = 0; j < 32; ++j)
    v[j] = fmaf(x0, w1[j], fmaf(x1, w1[32+j], x2 * w1[64+j]));
  float s0=0.f, s1=0.f, d0=0.f, d1=0.f;
#pragma unroll
  for (int k = 0; k < 16; ++k) {
    s0 = fmaf(v[k],    atts[k],    s0);
    d0 = fmaf(v[k],    attd[k],    d0);
    s1 = fmaf(v[16+k], atts[16+k], s1);
    d1 = fmaf(v[16+k], attd[16+k], d1);
  }
  float4* o = reinterpret_cast<float4*>(xl + (size_t)i*32);
#pragma unroll
  for (int q = 0; q < 8; ++q)
    o[q] = make_float4(v[4*q], v[4*q+1], v[4*q+2], v[4*q+3]);
  as_[2*i] = s0; as_[2*i+1] = s1;
  ad_[2*i] = d0; ad_[2*i+1] = d1;
}

// ---------------- Bucket histogram ----------------------------------------
__global__ void k_hist(const int* __restrict__ edst, unsigned* __restrict__ gcount,
                       int E, int nb) {
  __shared__ unsigned hist[MAXNB];
  for (int b = threadIdx.x; b < nb; b += blockDim.x) hist[b] = 0u;
  __syncthreads();
  int stride = gridDim.x * blockDim.x;
  for (int e = blockIdx.x * blockDim.x + threadIdx.x; e < E; e += stride)
    atomicAdd(&hist[((unsigned)edst[e]) >> BUCKET_BITS], 1u);
  __syncthreads();
  for (int b = threadIdx.x; b < nb; b += blockDim.x)
    if (hist[b]) atomicAdd(&gcount[b], hist[b]);
}

// ---------------- Exclusive scan over buckets (1 block) --------------------
__global__ void k_scanb(const unsigned* __restrict__ gcount,
                        unsigned* __restrict__ start, unsigned* __restrict__ cursor,
                        int nb) {
  __shared__ unsigned sm[MAXNB];
  int t = threadIdx.x;
  unsigned v = (t < nb) ? gcount[t] : 0u;
  sm[t] = v; __syncthreads();
  for (int off = 1; off < MAXNB; off <<= 1) {
    unsigned u = (t >= off) ? sm[t - off] : 0u;
    __syncthreads();
    sm[t] += u;
    __syncthreads();
  }
  if (t < nb) { unsigned excl = sm[t] - v; start[t] = excl; cursor[t] = excl; }
  if (t == nb - 1) start[nb] = sm[t];   // total = E
}

// ---------------- Partition edges into dst-buckets -------------------------
// packed[slot] = (dst_local << 17) | src  (u32; needs n <= 131072)
__global__ void k_part(const int* __restrict__ esrc, const int* __restrict__ edst,
                       unsigned* __restrict__ cursor, unsigned* __restrict__ packed,
                       int E, int nb) {
  __shared__ unsigned hist[MAXNB], base[MAXNB], offs[MAXNB];
  int e0 = blockIdx.x * PART_CHUNK;
  int e1 = min(E, e0 + PART_CHUNK);
  for (int b = threadIdx.x; b < nb; b += blockDim.x) { hist[b] = 0u; offs[b] = 0u; }
  __syncthreads();
  for (int e = e0 + threadIdx.x; e < e1; e += blockDim.x)
    atomicAdd(&hist[((unsigned)edst[e]) >> BUCKET_BITS], 1u);
  __syncthreads();
  for (int b = threadIdx.x; b < nb; b += blockDim.x)
    base[b] = hist[b] ? atomicAdd(&cursor[b], hist[b]) : 0u;
  __syncthreads();
  for (int e = e0 + threadIdx.x; e < e1; e += blockDim.x) {
    unsigned d = (unsigned)edst[e];
    unsigned b = d >> BUCKET_BITS;
    unsigned r = atomicAdd(&offs[b], 1u);
    packed[base[b] + r] = ((d & (BNODES - 1u)) << 17) | (unsigned)esrc[e];
  }
}

// ---------------- Bucket edge pass: LDS accumulation, no global atomics ----
// num[d,c] = sum_{s in nbrs(d)} xl[s,c]*e(s,d);  den likewise (self-loop added later)
template<int CTOT, int CPH, int LPE>
__global__ void k_bucket(const unsigned* __restrict__ start,
                         const unsigned* __restrict__ packed,
                         const float* __restrict__ xl,   // [N,CTOT]
                         const float* __restrict__ as_,  // [N,2]
                         const float* __restrict__ ad_,  // [N,2]
                         float* __restrict__ num,        // [N,CTOT]
                         float* __restrict__ den,        // [N,2]
                         int n) {
  __shared__ float acc[BNODES * CTOT];
  __shared__ float dsum[BNODES * 2];
  int b = blockIdx.x;
  int base = b << BUCKET_BITS;
  int nNodes = min(BNODES, n - base);
  for (int i = threadIdx.x; i < BNODES * CTOT; i += blockDim.x) acc[i] = 0.f;
  for (int i = threadIdx.x; i < BNODES * 2; i += blockDim.x) dsum[i] = 0.f;
  __syncthreads();
  unsigned s0 = start[b], s1 = start[b + 1];
  int c = threadIdx.x & (LPE - 1);
  int grp = threadIdx.x / LPE;
  int ngrp = blockDim.x / LPE;
  int h = (c < CTOT) ? c / CPH : 0;
  for (unsigned j = s0 + grp; j < s1; j += ngrp) {
    unsigned pk = packed[j];
    unsigned s = pk & 0x1FFFFu;
    unsigned local = pk >> 17;
    float a = as_[2*s + h] + ad_[2*(base + (int)local) + h];
    a = (a >= 0.f) ? a : NEG_SLOPE * a;
    float ee = __expf(a);
    if (c < CTOT) atomicAdd(&acc[local*CTOT + c], xl[(size_t)s*CTOT + c] * ee);
    if (c == 0 || c == CPH) atomicAdd(&dsum[local*2 + h], ee);
  }
  __syncthreads();
  for (int i = threadIdx.x; i < nNodes * CTOT; i += blockDim.x)
    num[(size_t)base*CTOT + i] = acc[i];
  for (int i = threadIdx.x; i < nNodes * 2; i += blockDim.x)
    den[(size_t)base*2 + i] = dsum[i];
}

// ---------------- L1 finalize (+self-loop) + ReLU + L2 transform -----------
__global__ void k_node2(const float* __restrict__ num1,  // [N,32]
                        const float* __restrict__ den1,  // [N,2]
                        const float* __restrict__ xl1,   // [N,32]
                        const float* __restrict__ as1,   // [N,2]
                        const float* __restrict__ ad1,   // [N,2]
                        const float* __restrict__ b1,    // [32]
                        const float* __restrict__ w2,    // [32,14]
                        const float* __restrict__ atts,  // [2,7]
                        const float* __restrict__ attd,  // [2,7]
                        float* __restrict__ xl2,         // [N,14]
                        float* __restrict__ as2,         // [N,2]
                        float* __restrict__ ad2,         // [N,2]
                        int n) {
  int i = blockIdx.x * blockDim.x + threadIdx.x;
  if (i >= n) return;
  // self-loop coefficients
  float a0 = as1[2*i]   + ad1[2*i];
  float a1 = as1[2*i+1] + ad1[2*i+1];
  a0 = (a0 >= 0.f) ? a0 : NEG_SLOPE * a0;
  a1 = (a1 >= 0.f) ? a1 : NEG_SLOPE * a1;
  float e0 = __expf(a0), e1 = __expf(a1);
  float dh0 = den1[2*i]   + e0 + 1e-16f;
  float dh1 = den1[2*i+1] + e1 + 1e-16f;
  const float4* nr = reinterpret_cast<const float4*>(num1 + (size_t)i*32);
  const float4* xr = reinterpret_cast<const float4*>(xl1  + (size_t)i*32);
  float hbuf[32];
#pragma unroll
  for (int q = 0; q < 8; ++q) {
    float4 v = nr[q];
    float4 xv = xr[q];
    float es = (q < 4) ? e0 : e1;
    float dd = (q < 4) ? dh0 : dh1;
    float t;
    t = (v.x + xv.x*es)/dd + b1[4*q];   hbuf[4*q]   = t > 0.f ? t : 0.f;
    t = (v.y + xv.y*es)/dd + b1[4*q+1]; hbuf[4*q+1] = t > 0.f ? t : 0.f;
    t = (v.z + xv.z*es)/dd + b1[4*q+2]; hbuf[4*q+2] = t > 0.f ? t : 0.f;
    t = (v.w + xv.w*es)/dd + b1[4*q+3]; hbuf[4*q+3] = t > 0.f ? t : 0.f;
  }
  float o[14];
#pragma unroll
  for (int j = 0; j < 14; ++j) o[j] = 0.f;
#pragma unroll
  for (int ch = 0; ch < 32; ++ch) {
#pragma unroll
    for (int j = 0; j < 14; ++j)
      o[j] = fmaf(hbuf[ch], w2[14*ch + j], o[j]);
  }
  float s0=0.f, s1=0.f, d0=0.f, d1=0.f;
#pragma unroll
  for (int k = 0; k < 7; ++k) {
    s0 = fmaf(o[k],   atts[k],   s0);
    d0 = fmaf(o[k],   attd[k],   d0);
    s1 = fmaf(o[7+k], atts[7+k], s1);
    d1 = fmaf(o[7+k], attd[7+k], d1);
  }
  float* xo = xl2 + (size_t)i*14;
#pragma unroll
  for (int j = 0; j < 14; ++j) xo[j] = o[j];
  as2[2*i] = s0; as2[2*i+1] = s1;
  ad2[2*i] = d0; ad2[2*i+1] = d1;
}

// ---------------- L2 finalize (+self-loop): head-mean + bias + log_softmax -
__global__ void k_final(const float* __restrict__ num2,  // [N,14]
                        const float* __restrict__ den2,  // [N,2]
                        const float* __restrict__ xl2,   // [N,14]
                        const float* __restrict__ as2,   // [N,2]
                        const float* __restrict__ ad2,   // [N,2]
                        const float* __restrict__ b2,    // [7]
                        float* __restrict__ out,         // [N,7]
                        int n) {
  int i = blockIdx.x * blockDim.x + threadIdx.x;
  if (i >= n) return;
  float a0 = as2[2*i]   + ad2[2*i];
  float a1 = as2[2*i+1] + ad2[2*i+1];
  a0 = (a0 >= 0.f) ? a0 : NEG_SLOPE * a0;
  a1 = (a1 >= 0.f) ? a1 : NEG_SLOPE * a1;
  float e0 = __expf(a0), e1 = __expf(a1);
  float d0 = den2[2*i]   + e0 + 1e-16f;
  float d1 = den2[2*i+1] + e1 + 1e-16f;
  const float* nr = num2 + (size_t)i*14;
  const float* xr = xl2  + (size_t)i*14;
  float v[7];
#pragma unroll
  for (int c = 0; c < 7; ++c)
    v[c] = 0.5f*((nr[c] + xr[c]*e0)/d0 + (nr[7+c] + xr[7+c]*e1)/d1) + b2[c];
  float m = v[0];
#pragma unroll
  for (int c = 1; c < 7; ++c) m = fmaxf(m, v[c]);
  float s = 0.f;
#pragma unroll
  for (int c = 0; c < 7; ++c) s += __expf(v[c]-m);
  float ls = __logf(s);
#pragma unroll
  for (int c = 0; c < 7; ++c) out[(size_t)i*7+c] = v[c]-m-ls;
}

extern "C" void kernel_launch(void* const* d_in, const int* in_sizes, int n_in,
                              void* d_out, int out_size, void* d_ws, size_t ws_size,
                              hipStream_t stream) {
  const float* x    = (const float*)d_in[0];
  const int*   ei   = (const int*)  d_in[1];
  const float* w1   = (const float*)d_in[2];
  const float* as1w = (const float*)d_in[3];
  const float* ad1w = (const float*)d_in[4];
  const float* b1   = (const float*)d_in[5];
  const float* w2   = (const float*)d_in[6];
  const float* as2w = (const float*)d_in[7];
  const float* ad2w = (const float*)d_in[8];
  const float* b2   = (const float*)d_in[9];
  float* out = (float*)d_out;

  const int n = in_sizes[0] / 3;
  const int E = in_sizes[1] / 2;
  const int* esrc = ei;
  const int* edst = ei + E;
  const int nb = (n + BNODES - 1) >> BUCKET_BITS;   // 782 for n=100000

  const size_t N = (size_t)n;
  float* ws = (float*)d_ws;
  // float workspace layout:
  float* xl1  = ws;             // 32N
  float* as1  = ws + 32*N;      //  2N
  float* ad1  = ws + 34*N;      //  2N
  float* xl2  = ws + 36*N;      // 14N
  float* as2  = ws + 50*N;      //  2N
  float* ad2  = ws + 52*N;      //  2N
  float* num1 = ws + 54*N;      // 32N
  float* den1 = ws + 86*N;      //  2N
  float* num2 = ws + 88*N;      // 14N
  float* den2 = ws + 102*N;     //  2N
  unsigned* gcount = (unsigned*)(ws + 104*N);            // MAXNB+1
  unsigned* bstart = gcount + (MAXNB + 1);               // MAXNB+1
  unsigned* bcur   = bstart + (MAXNB + 1);               // MAXNB+1
  unsigned* packed = bcur   + (MAXNB + 1);               // E

  const int nbN = (n + 255) / 256;
  const int nbP = (E + PART_CHUNK - 1) / PART_CHUNK;

  hipMemsetAsync(gcount, 0, (nb + 1) * sizeof(unsigned), stream);

  k_node1<<<nbN, 256, 0, stream>>>(x, w1, as1w, ad1w, xl1, as1, ad1, n);

  // bucket partition (shared by both layers)
  k_hist <<<1024, 256, 0, stream>>>(edst, gcount, E, nb);
  k_scanb<<<1, MAXNB, 0, stream>>>(gcount, bstart, bcur, nb);
  k_part <<<nbP, 256, 0, stream>>>(esrc, edst, bcur, packed, E, nb);

  // Layer 1: 32 lanes per edge
  k_bucket<32,16,32><<<nb, 256, 0, stream>>>(bstart, packed, xl1, as1, ad1, num1, den1, n);
  k_node2<<<nbN, 256, 0, stream>>>(num1, den1, xl1, as1, ad1, b1, w2, as2w, ad2w, xl2, as2, ad2, n);

  // Layer 2: 16 lanes per edge (14 active)
  k_bucket<14,7,16><<<nb, 256, 0, stream>>>(bstart, packed, xl2, as2, ad2, num2, den2, n);
  k_final<<<nbN, 256, 0, stream>>>(num2, den2, xl2, as2, ad2, b2, out, n);
}

// Round 4
// 441.372 us; speedup vs baseline: 2.8375x; 2.8375x over previous
//
#include <hip/hip_runtime.h>

static constexpr float NEG_SLOPE = 0.2f;
#define BUCKET_BITS 7
#define BNODES (1 << BUCKET_BITS)      // 128 nodes per bucket
#define MAXNB 1024                     // supports n <= 131072 (src fits 17 bits)
#define PART_CHUNK 16384
#define SORT_CAP 6144                  // bucket-edge LDS staging capacity

// ---------------- Layer-1 node transform: xl1 = x@W1, a_src/a_dst ----------
__global__ void k_node1(const float* __restrict__ x,
                        const float* __restrict__ w1,    // [3,32]
                        const float* __restrict__ atts,  // [2,16]
                        const float* __restrict__ attd,  // [2,16]
                        float* __restrict__ xl,          // [N,32]
                        float* __restrict__ as_,         // [N,2]
                        float* __restrict__ ad_,         // [N,2]
                        int n) {
  int i = blockIdx.x * blockDim.x + threadIdx.x;
  if (i >= n) return;
  float x0 = x[3*i], x1 = x[3*i+1], x2 = x[3*i+2];
  float v[32];
#pragma unroll
  for (int j = 0; j < 32; ++j)
    v[j] = fmaf(x0, w1[j], fmaf(x1, w1[32+j], x2 * w1[64+j]));
  float s0=0.f, s1=0.f, d0=0.f, d1=0.f;
#pragma unroll
  for (int k = 0; k < 16; ++k) {
    s0 = fmaf(v[k],    atts[k],    s0);
    d0 = fmaf(v[k],    attd[k],    d0);
    s1 = fmaf(v[16+k], atts[16+k], s1);
    d1 = fmaf(v[16+k], attd[16+k], d1);
  }
  float4* o = reinterpret_cast<float4*>(xl + (size_t)i*32);
#pragma unroll
  for (int q = 0; q < 8; ++q)
    o[q] = make_float4(v[4*q], v[4*q+1], v[4*q+2], v[4*q+3]);
  as_[2*i] = s0; as_[2*i+1] = s1;
  ad_[2*i] = d0; ad_[2*i+1] = d1;
}

// ---------------- Bucket histogram (LDS-staged) -----------------------------
__global__ void k_hist(const int* __restrict__ edst, unsigned* __restrict__ gcount,
                       int E, int nb) {
  __shared__ unsigned hist[MAXNB];
  for (int b = threadIdx.x; b < nb; b += blockDim.x) hist[b] = 0u;
  __syncthreads();
  int stride = gridDim.x * blockDim.x;
  for (int e = blockIdx.x * blockDim.x + threadIdx.x; e < E; e += stride)
    atomicAdd(&hist[((unsigned)edst[e]) >> BUCKET_BITS], 1u);
  __syncthreads();
  for (int b = threadIdx.x; b < nb; b += blockDim.x)
    if (hist[b]) atomicAdd(&gcount[b], hist[b]);
}

// ---------------- Exclusive scan over buckets (1 block) --------------------
__global__ void k_scanb(const unsigned* __restrict__ gcount,
                        unsigned* __restrict__ start, unsigned* __restrict__ cursor,
                        int nb) {
  __shared__ unsigned sm[MAXNB];
  int t = threadIdx.x;
  unsigned v = (t < nb) ? gcount[t] : 0u;
  sm[t] = v; __syncthreads();
  for (int off = 1; off < MAXNB; off <<= 1) {
    unsigned u = (t >= off) ? sm[t - off] : 0u;
    __syncthreads();
    sm[t] += u;
    __syncthreads();
  }
  if (t < nb) { unsigned excl = sm[t] - v; start[t] = excl; cursor[t] = excl; }
  if (t == nb - 1) start[nb] = sm[t];   // total = E
}

// ---------------- Partition edges into dst-bucket runs ---------------------
// packed[slot] = (dst_local << 17) | src  (u32; needs n <= 131072)
__global__ void k_part(const int* __restrict__ esrc, const int* __restrict__ edst,
                       unsigned* __restrict__ cursor, unsigned* __restrict__ packed,
                       int E, int nb) {
  __shared__ unsigned hist[MAXNB], base[MAXNB], offs[MAXNB];
  int e0 = blockIdx.x * PART_CHUNK;
  int e1 = min(E, e0 + PART_CHUNK);
  for (int b = threadIdx.x; b < nb; b += blockDim.x) { hist[b] = 0u; offs[b] = 0u; }
  __syncthreads();
  for (int e = e0 + threadIdx.x; e < e1; e += blockDim.x)
    atomicAdd(&hist[((unsigned)edst[e]) >> BUCKET_BITS], 1u);
  __syncthreads();
  for (int b = threadIdx.x; b < nb; b += blockDim.x)
    base[b] = hist[b] ? atomicAdd(&cursor[b], hist[b]) : 0u;
  __syncthreads();
  for (int e = e0 + threadIdx.x; e < e1; e += blockDim.x) {
    unsigned d = (unsigned)edst[e];
    unsigned b = d >> BUCKET_BITS;
    unsigned r = atomicAdd(&offs[b], 1u);
    packed[base[b] + r] = ((d & (BNODES - 1u)) << 17) | (unsigned)esrc[e];
  }
}

// ---------------- Per-bucket LDS sort: packed run -> node-sorted col + rp --
__global__ void k_sortb(const unsigned* __restrict__ bstart,
                        const unsigned* __restrict__ packed,
                        int* __restrict__ col,
                        unsigned* __restrict__ rp,
                        int n) {
  __shared__ unsigned stage_in[SORT_CAP];
  __shared__ unsigned stage_out[SORT_CAP];
  __shared__ unsigned cnt[BNODES], excl[BNODES], off[BNODES];
  int b = blockIdx.x;
  unsigned s0 = bstart[b], s1 = bstart[b + 1];
  int size = (int)(s1 - s0);
  int t = threadIdx.x;
  if (t < BNODES) cnt[t] = 0u;
  __syncthreads();
  bool lds_path = (size <= SORT_CAP);
  if (lds_path) {
    for (int i = t; i < size; i += blockDim.x) {
      unsigned pk = packed[s0 + i];
      stage_in[i] = pk;
      atomicAdd(&cnt[pk >> 17], 1u);
    }
  } else {
    for (int i = t; i < size; i += blockDim.x)
      atomicAdd(&cnt[packed[s0 + i] >> 17], 1u);
  }
  __syncthreads();
  if (t == 0) {                       // serial 128-entry exclusive scan (cheap)
    unsigned run = 0;
#pragma unroll 4
    for (int i = 0; i < BNODES; ++i) { excl[i] = run; run += cnt[i]; }
  }
  __syncthreads();
  if (t < BNODES) off[t] = excl[t];
  __syncthreads();
  if (lds_path) {
    for (int i = t; i < size; i += blockDim.x) {
      unsigned pk = stage_in[i];
      unsigned slot = atomicAdd(&off[pk >> 17], 1u);
      stage_out[slot] = pk & 0x1FFFFu;
    }
    __syncthreads();
    for (int i = t; i < size; i += blockDim.x)
      col[s0 + i] = (int)stage_out[i];
  } else {                            // oversize fallback: direct scattered writes
    for (int i = t; i < size; i += blockDim.x) {
      unsigned pk = packed[s0 + i];
      unsigned slot = atomicAdd(&off[pk >> 17], 1u);
      col[s0 + slot] = (int)(pk & 0x1FFFFu);
    }
  }
  int base = b << BUCKET_BITS;
  if (t < BNODES && base + t < n) rp[base + t] = s0 + excl[t];
}

// ---------------- Gather edge pass: LPE lanes per dst node, no atomics -----
template<int CTOT, int CPH, int LPE>
__global__ void k_gather(const unsigned* __restrict__ rp,
                         const int* __restrict__ col,
                         const float* __restrict__ xl,   // [N,CTOT]
                         const float* __restrict__ as_,  // [N,2]
                         const float* __restrict__ ad_,  // [N,2]
                         float* __restrict__ num,        // [N,CTOT]
                         float* __restrict__ den,        // [N,2]
                         int n, int E) {
  int d = blockIdx.x * (blockDim.x / LPE) + threadIdx.x / LPE;
  int c = threadIdx.x & (LPE - 1);
  if (d >= n) return;
  int h = (c < CTOT) ? c / CPH : 0;
  float adh = ad_[2*d + h];
  float acc = 0.f, dsum = 0.f;
  unsigned jb = rp[d];
  unsigned je = (d + 1 < n) ? rp[d + 1] : (unsigned)E;
  for (unsigned j = jb; j < je; ++j) {
    int s = col[j];
    float a = as_[2*s + h] + adh;
    a = (a >= 0.f) ? a : NEG_SLOPE * a;
    float ee = __expf(a);
    if (c < CTOT) acc = fmaf(xl[(size_t)s*CTOT + c], ee, acc);
    dsum += ee;
  }
  if (c < CTOT) num[(size_t)d*CTOT + c] = acc;
  if (c == 0)    den[2*d]     = dsum;
  if (c == CPH)  den[2*d + 1] = dsum;
}

// ---------------- L1 finalize (+self-loop) + ReLU + L2 transform -----------
__global__ void k_node2(const float* __restrict__ num1,  // [N,32]
                        const float* __restrict__ den1,  // [N,2]
                        const float* __restrict__ xl1,   // [N,32]
                        const float* __restrict__ as1,   // [N,2]
                        const float* __restrict__ ad1,   // [N,2]
                        const float* __restrict__ b1,    // [32]
                        const float* __restrict__ w2,    // [32,14]
                        const float* __restrict__ atts,  // [2,7]
                        const float* __restrict__ attd,  // [2,7]
                        float* __restrict__ xl2,         // [N,14]
                        float* __restrict__ as2,         // [N,2]
                        float* __restrict__ ad2,         // [N,2]
                        int n) {
  int i = blockIdx.x * blockDim.x + threadIdx.x;
  if (i >= n) return;
  float a0 = as1[2*i]   + ad1[2*i];
  float a1 = as1[2*i+1] + ad1[2*i+1];
  a0 = (a0 >= 0.f) ? a0 : NEG_SLOPE * a0;
  a1 = (a1 >= 0.f) ? a1 : NEG_SLOPE * a1;
  float e0 = __expf(a0), e1 = __expf(a1);
  float dh0 = den1[2*i]   + e0 + 1e-16f;
  float dh1 = den1[2*i+1] + e1 + 1e-16f;
  const float4* nr = reinterpret_cast<const float4*>(num1 + (size_t)i*32);
  const float4* xr = reinterpret_cast<const float4*>(xl1  + (size_t)i*32);
  float hbuf[32];
#pragma unroll
  for (int q = 0; q < 8; ++q) {
    float4 v = nr[q];
    float4 xv = xr[q];
    float es = (q < 4) ? e0 : e1;
    float dd = (q < 4) ? dh0 : dh1;
    float t;
    t = (v.x + xv.x*es)/dd + b1[4*q];   hbuf[4*q]   = t > 0.f ? t : 0.f;
    t = (v.y + xv.y*es)/dd + b1[4*q+1]; hbuf[4*q+1] = t > 0.f ? t : 0.f;
    t = (v.z + xv.z*es)/dd + b1[4*q+2]; hbuf[4*q+2] = t > 0.f ? t : 0.f;
    t = (v.w + xv.w*es)/dd + b1[4*q+3]; hbuf[4*q+3] = t > 0.f ? t : 0.f;
  }
  float o[14];
#pragma unroll
  for (int j = 0; j < 14; ++j) o[j] = 0.f;
#pragma unroll
  for (int ch = 0; ch < 32; ++ch) {
#pragma unroll
    for (int j = 0; j < 14; ++j)
      o[j] = fmaf(hbuf[ch], w2[14*ch + j], o[j]);
  }
  float s0=0.f, s1=0.f, d0=0.f, d1=0.f;
#pragma unroll
  for (int k = 0; k < 7; ++k) {
    s0 = fmaf(o[k],   atts[k],   s0);
    d0 = fmaf(o[k],   attd[k],   d0);
    s1 = fmaf(o[7+k], atts[7+k], s1);
    d1 = fmaf(o[7+k], attd[7+k], d1);
  }
  float* xo = xl2 + (size_t)i*14;
#pragma unroll
  for (int j = 0; j < 14; ++j) xo[j] = o[j];
  as2[2*i] = s0; as2[2*i+1] = s1;
  ad2[2*i] = d0; ad2[2*i+1] = d1;
}

// ---------------- L2 finalize (+self-loop): head-mean + bias + log_softmax -
__global__ void k_final(const float* __restrict__ num2,  // [N,14]
                        const float* __restrict__ den2,  // [N,2]
                        const float* __restrict__ xl2,   // [N,14]
                        const float* __restrict__ as2,   // [N,2]
                        const float* __restrict__ ad2,   // [N,2]
                        const float* __restrict__ b2,    // [7]
                        float* __restrict__ out,         // [N,7]
                        int n) {
  int i = blockIdx.x * blockDim.x + threadIdx.x;
  if (i >= n) return;
  float a0 = as2[2*i]   + ad2[2*i];
  float a1 = as2[2*i+1] + ad2[2*i+1];
  a0 = (a0 >= 0.f) ? a0 : NEG_SLOPE * a0;
  a1 = (a1 >= 0.f) ? a1 : NEG_SLOPE * a1;
  float e0 = __expf(a0), e1 = __expf(a1);
  float d0 = den2[2*i]   + e0 + 1e-16f;
  float d1 = den2[2*i+1] + e1 + 1e-16f;
  const float* nr = num2 + (size_t)i*14;
  const float* xr = xl2  + (size_t)i*14;
  float v[7];
#pragma unroll
  for (int c = 0; c < 7; ++c)
    v[c] = 0.5f*((nr[c] + xr[c]*e0)/d0 + (nr[7+c] + xr[7+c]*e1)/d1) + b2[c];
  float m = v[0];
#pragma unroll
  for (int c = 1; c < 7; ++c) m = fmaxf(m, v[c]);
  float s = 0.f;
#pragma unroll
  for (int c = 0; c < 7; ++c) s += __expf(v[c]-m);
  float ls = __logf(s);
#pragma unroll
  for (int c = 0; c < 7; ++c) out[(size_t)i*7+c] = v[c]-m-ls;
}

extern "C" void kernel_launch(void* const* d_in, const int* in_sizes, int n_in,
                              void* d_out, int out_size, void* d_ws, size_t ws_size,
                              hipStream_t stream) {
  const float* x    = (const float*)d_in[0];
  const int*   ei   = (const int*)  d_in[1];
  const float* w1   = (const float*)d_in[2];
  const float* as1w = (const float*)d_in[3];
  const float* ad1w = (const float*)d_in[4];
  const float* b1   = (const float*)d_in[5];
  const float* w2   = (const float*)d_in[6];
  const float* as2w = (const float*)d_in[7];
  const float* ad2w = (const float*)d_in[8];
  const float* b2   = (const float*)d_in[9];
  float* out = (float*)d_out;

  const int n = in_sizes[0] / 3;
  const int E = in_sizes[1] / 2;
  const int* esrc = ei;
  const int* edst = ei + E;
  const int nb = (n + BNODES - 1) >> BUCKET_BITS;   // 782 for n=100000

  const size_t N = (size_t)n;
  float* ws = (float*)d_ws;
  // float workspace layout:
  float* xl1  = ws;             // 32N
  float* as1  = ws + 32*N;      //  2N
  float* ad1  = ws + 34*N;      //  2N
  float* xl2  = ws + 36*N;      // 14N
  float* as2  = ws + 50*N;      //  2N
  float* ad2  = ws + 52*N;      //  2N
  float* num1 = ws + 54*N;      // 32N
  float* den1 = ws + 86*N;      //  2N
  float* num2 = ws + 88*N;      // 14N
  float* den2 = ws + 102*N;     //  2N
  // packed aliases num1.. (dead before gather1 writes num1): E u32 <= 48N floats
  unsigned* packed = (unsigned*)num1;
  unsigned* gcount = (unsigned*)(ws + 104*N);            // MAXNB+1
  unsigned* bstart = gcount + (MAXNB + 1);               // MAXNB+1
  unsigned* bcur   = bstart + (MAXNB + 1);               // MAXNB+1
  int*      col    = (int*)(bcur + (MAXNB + 1));         // E
  unsigned* rp     = (unsigned*)(col + E);               // N

  const int nbN = (n + 255) / 256;
  const int nbP = (E + PART_CHUNK - 1) / PART_CHUNK;

  hipMemsetAsync(gcount, 0, (nb + 1) * sizeof(unsigned), stream);

  k_node1<<<nbN, 256, 0, stream>>>(x, w1, as1w, ad1w, xl1, as1, ad1, n);

  // two-level CSR build (shared by both layers), all writes coalesced/run-grouped
  k_hist <<<1024, 256, 0, stream>>>(edst, gcount, E, nb);
  k_scanb<<<1, MAXNB, 0, stream>>>(gcount, bstart, bcur, nb);
  k_part <<<nbP, 256, 0, stream>>>(esrc, edst, bcur, packed, E, nb);
  k_sortb<<<nb, 256, 0, stream>>>(bstart, packed, col, rp, n);

  // Layer 1: 32 lanes per node (packed region now dead; num1 reused)
  k_gather<32,16,32><<<(n*32 + 255)/256, 256, 0, stream>>>(rp, col, xl1, as1, ad1, num1, den1, n, E);
  k_node2<<<nbN, 256, 0, stream>>>(num1, den1, xl1, as1, ad1, b1, w2, as2w, ad2w, xl2, as2, ad2, n);

  // Layer 2: 16 lanes per node (14 active)
  k_gather<14,7,16><<<(n*16 + 255)/256, 256, 0, stream>>>(rp, col, xl2, as2, ad2, num2, den2, n, E);
  k_final<<<nbN, 256, 0, stream>>>(num2, den2, xl2, as2, ad2, b2, out, n);
}

// Round 5
// 241.545 us; speedup vs baseline: 5.1849x; 1.8273x over previous
//
#include <hip/hip_runtime.h>
#include <hip/hip_fp16.h>

static constexpr float NEG_SLOPE = 0.2f;
#define BUCKET_BITS 7
#define BNODES (1 << BUCKET_BITS)      // 128 nodes per bucket
#define MAXNB 1024                     // supports n <= 131072 (src fits 17 bits)
#define PART_CHUNK 16384
#define SORT_CAP 6144                  // bucket-edge LDS staging capacity

// ---------------- Layer-1 node transform: xl1(fp16) = x@W1, a_src/a_dst ----
__global__ void k_node1(const float* __restrict__ x,
                        const float* __restrict__ w1,    // [3,32]
                        const float* __restrict__ atts,  // [2,16]
                        const float* __restrict__ attd,  // [2,16]
                        __half2* __restrict__ xlh,       // [N,16] half2
                        float* __restrict__ as_,         // [N,2]
                        float* __restrict__ ad_,         // [N,2]
                        int n) {
  int i = blockIdx.x * blockDim.x + threadIdx.x;
  if (i >= n) return;
  float x0 = x[3*i], x1 = x[3*i+1], x2 = x[3*i+2];
  float v[32];
#pragma unroll
  for (int j = 0; j < 32; ++j)
    v[j] = fmaf(x0, w1[j], fmaf(x1, w1[32+j], x2 * w1[64+j]));
  float s0=0.f, s1=0.f, d0=0.f, d1=0.f;
#pragma unroll
  for (int k = 0; k < 16; ++k) {
    s0 = fmaf(v[k],    atts[k],    s0);
    d0 = fmaf(v[k],    attd[k],    d0);
    s1 = fmaf(v[16+k], atts[16+k], s1);
    d1 = fmaf(v[16+k], attd[16+k], d1);
  }
  __half2* o = xlh + (size_t)i*16;
#pragma unroll
  for (int q = 0; q < 16; ++q)
    o[q] = __floats2half2_rn(v[2*q], v[2*q+1]);
  as_[2*i] = s0; as_[2*i+1] = s1;
  ad_[2*i] = d0; ad_[2*i+1] = d1;
}

// ---------------- Bucket histogram (LDS-staged) -----------------------------
__global__ void k_hist(const int* __restrict__ edst, unsigned* __restrict__ gcount,
                       int E, int nb) {
  __shared__ unsigned hist[MAXNB];
  for (int b = threadIdx.x; b < nb; b += blockDim.x) hist[b] = 0u;
  __syncthreads();
  int stride = gridDim.x * blockDim.x;
  for (int e = blockIdx.x * blockDim.x + threadIdx.x; e < E; e += stride)
    atomicAdd(&hist[((unsigned)edst[e]) >> BUCKET_BITS], 1u);
  __syncthreads();
  for (int b = threadIdx.x; b < nb; b += blockDim.x)
    if (hist[b]) atomicAdd(&gcount[b], hist[b]);
}

// ---------------- Exclusive scan over buckets (1 block) --------------------
__global__ void k_scanb(const unsigned* __restrict__ gcount,
                        unsigned* __restrict__ start, unsigned* __restrict__ cursor,
                        int nb) {
  __shared__ unsigned sm[MAXNB];
  int t = threadIdx.x;
  unsigned v = (t < nb) ? gcount[t] : 0u;
  sm[t] = v; __syncthreads();
  for (int off = 1; off < MAXNB; off <<= 1) {
    unsigned u = (t >= off) ? sm[t - off] : 0u;
    __syncthreads();
    sm[t] += u;
    __syncthreads();
  }
  if (t < nb) { unsigned excl = sm[t] - v; start[t] = excl; cursor[t] = excl; }
  if (t == nb - 1) start[nb] = sm[t];   // total = E
}

// ---------------- Partition edges into dst-bucket runs ---------------------
// packed[slot] = (dst_local << 17) | src  (u32; needs n <= 131072)
__global__ void k_part(const int* __restrict__ esrc, const int* __restrict__ edst,
                       unsigned* __restrict__ cursor, unsigned* __restrict__ packed,
                       int E, int nb) {
  __shared__ unsigned hist[MAXNB], base[MAXNB], offs[MAXNB];
  int e0 = blockIdx.x * PART_CHUNK;
  int e1 = min(E, e0 + PART_CHUNK);
  for (int b = threadIdx.x; b < nb; b += blockDim.x) { hist[b] = 0u; offs[b] = 0u; }
  __syncthreads();
  for (int e = e0 + threadIdx.x; e < e1; e += blockDim.x)
    atomicAdd(&hist[((unsigned)edst[e]) >> BUCKET_BITS], 1u);
  __syncthreads();
  for (int b = threadIdx.x; b < nb; b += blockDim.x)
    base[b] = hist[b] ? atomicAdd(&cursor[b], hist[b]) : 0u;
  __syncthreads();
  for (int e = e0 + threadIdx.x; e < e1; e += blockDim.x) {
    unsigned d = (unsigned)edst[e];
    unsigned b = d >> BUCKET_BITS;
    unsigned r = atomicAdd(&offs[b], 1u);
    packed[base[b] + r] = ((d & (BNODES - 1u)) << 17) | (unsigned)esrc[e];
  }
}

// ---------------- Per-bucket LDS sort: packed run -> node-sorted col + rp --
__global__ void k_sortb(const unsigned* __restrict__ bstart,
                        const unsigned* __restrict__ packed,
                        int* __restrict__ col,
                        unsigned* __restrict__ rp,
                        int n) {
  __shared__ unsigned stage_in[SORT_CAP];
  __shared__ unsigned stage_out[SORT_CAP];
  __shared__ unsigned cnt[BNODES], excl[BNODES], off[BNODES];
  int b = blockIdx.x;
  unsigned s0 = bstart[b], s1 = bstart[b + 1];
  int size = (int)(s1 - s0);
  int t = threadIdx.x;
  if (t < BNODES) cnt[t] = 0u;
  __syncthreads();
  bool lds_path = (size <= SORT_CAP);
  if (lds_path) {
    for (int i = t; i < size; i += blockDim.x) {
      unsigned pk = packed[s0 + i];
      stage_in[i] = pk;
      atomicAdd(&cnt[pk >> 17], 1u);
    }
  } else {
    for (int i = t; i < size; i += blockDim.x)
      atomicAdd(&cnt[packed[s0 + i] >> 17], 1u);
  }
  __syncthreads();
  if (t == 0) {                       // serial 128-entry exclusive scan (cheap)
    unsigned run = 0;
#pragma unroll 4
    for (int i = 0; i < BNODES; ++i) { excl[i] = run; run += cnt[i]; }
  }
  __syncthreads();
  if (t < BNODES) off[t] = excl[t];
  __syncthreads();
  if (lds_path) {
    for (int i = t; i < size; i += blockDim.x) {
      unsigned pk = stage_in[i];
      unsigned slot = atomicAdd(&off[pk >> 17], 1u);
      stage_out[slot] = pk & 0x1FFFFu;
    }
    __syncthreads();
    for (int i = t; i < size; i += blockDim.x)
      col[s0 + i] = (int)stage_out[i];
  } else {                            // oversize fallback: direct scattered writes
    for (int i = t; i < size; i += blockDim.x) {
      unsigned pk = packed[s0 + i];
      unsigned slot = atomicAdd(&off[pk >> 17], 1u);
      col[s0 + slot] = (int)(pk & 0x1FFFFu);
    }
  }
  int base = b << BUCKET_BITS;
  if (t < BNODES && base + t < n) rp[base + t] = s0 + excl[t];
}

// ---------------- Gather edge pass: LPE lanes/node, 2 ch/lane, unroll 4 ----
// PPH = half2 pairs per head; LPE = PPH*2 heads. No atomics.
template<int PPH, int LPE>
__global__ void k_gather(const unsigned* __restrict__ rp,
                         const int* __restrict__ col,
                         const __half2* __restrict__ xlh, // [N,LPE] half2
                         const float* __restrict__ as_,   // [N,2]
                         const float* __restrict__ ad_,   // [N,2]
                         float2* __restrict__ num,        // [N,LPE] float2
                         float* __restrict__ den,         // [N,2]
                         int n, int E) {
  int d = blockIdx.x * (blockDim.x / LPE) + threadIdx.x / LPE;
  int lane = threadIdx.x & (LPE - 1);
  if (d >= n) return;
  int h = lane / PPH;
  float adh = ad_[2*d + h];
  float acc0 = 0.f, acc1 = 0.f, dsum = 0.f;
  unsigned jb = rp[d];
  unsigned je = (d + 1 < n) ? rp[d + 1] : (unsigned)E;
  unsigned j = jb;
  for (; j + 4 <= je; j += 4) {
    int s0 = col[j], s1 = col[j+1], s2 = col[j+2], s3 = col[j+3];
    float b0 = as_[2*s0 + h], b1 = as_[2*s1 + h],
          b2 = as_[2*s2 + h], b3 = as_[2*s3 + h];
    __half2 x0 = xlh[(size_t)s0*LPE + lane];
    __half2 x1 = xlh[(size_t)s1*LPE + lane];
    __half2 x2 = xlh[(size_t)s2*LPE + lane];
    __half2 x3 = xlh[(size_t)s3*LPE + lane];
    float a;
    a = b0 + adh; a = (a >= 0.f) ? a : NEG_SLOPE*a; float e0 = __expf(a);
    a = b1 + adh; a = (a >= 0.f) ? a : NEG_SLOPE*a; float e1 = __expf(a);
    a = b2 + adh; a = (a >= 0.f) ? a : NEG_SLOPE*a; float e2 = __expf(a);
    a = b3 + adh; a = (a >= 0.f) ? a : NEG_SLOPE*a; float e3 = __expf(a);
    float2 f;
    f = __half22float2(x0); acc0 = fmaf(f.x, e0, acc0); acc1 = fmaf(f.y, e0, acc1);
    f = __half22float2(x1); acc0 = fmaf(f.x, e1, acc0); acc1 = fmaf(f.y, e1, acc1);
    f = __half22float2(x2); acc0 = fmaf(f.x, e2, acc0); acc1 = fmaf(f.y, e2, acc1);
    f = __half22float2(x3); acc0 = fmaf(f.x, e3, acc0); acc1 = fmaf(f.y, e3, acc1);
    dsum += (e0 + e1) + (e2 + e3);
  }
  for (; j < je; ++j) {
    int s = col[j];
    float a = as_[2*s + h] + adh;
    a = (a >= 0.f) ? a : NEG_SLOPE*a;
    float ee = __expf(a);
    float2 f = __half22float2(xlh[(size_t)s*LPE + lane]);
    acc0 = fmaf(f.x, ee, acc0); acc1 = fmaf(f.y, ee, acc1);
    dsum += ee;
  }
  num[(size_t)d*LPE + lane] = make_float2(acc0, acc1);
  if ((lane & (PPH - 1)) == 0) den[2*d + h] = dsum;
}

// ---------------- L1 finalize (+self-loop) + ReLU + L2 transform -----------
__global__ void k_node2(const float* __restrict__ num1,  // [N,32]
                        const float* __restrict__ den1,  // [N,2]
                        const __half2* __restrict__ xlh1,// [N,16]
                        const float* __restrict__ as1,   // [N,2]
                        const float* __restrict__ ad1,   // [N,2]
                        const float* __restrict__ b1,    // [32]
                        const float* __restrict__ w2,    // [32,14]
                        const float* __restrict__ atts,  // [2,7]
                        const float* __restrict__ attd,  // [2,7]
                        __half2* __restrict__ xlh2,      // [N,8] padded (8/head)
                        float* __restrict__ as2,         // [N,2]
                        float* __restrict__ ad2,         // [N,2]
                        int n) {
  int i = blockIdx.x * blockDim.x + threadIdx.x;
  if (i >= n) return;
  float a0 = as1[2*i]   + ad1[2*i];
  float a1 = as1[2*i+1] + ad1[2*i+1];
  a0 = (a0 >= 0.f) ? a0 : NEG_SLOPE * a0;
  a1 = (a1 >= 0.f) ? a1 : NEG_SLOPE * a1;
  float e0 = __expf(a0), e1 = __expf(a1);
  float dh0 = den1[2*i]   + e0 + 1e-16f;
  float dh1 = den1[2*i+1] + e1 + 1e-16f;
  const float4* nr = reinterpret_cast<const float4*>(num1 + (size_t)i*32);
  const __half2* xr = xlh1 + (size_t)i*16;
  float hbuf[32];
#pragma unroll
  for (int q = 0; q < 8; ++q) {
    float4 v = nr[q];
    float2 xa = __half22float2(xr[2*q]);
    float2 xb = __half22float2(xr[2*q+1]);
    float es = (q < 4) ? e0 : e1;
    float dd = (q < 4) ? dh0 : dh1;
    float t;
    t = (v.x + xa.x*es)/dd + b1[4*q];   hbuf[4*q]   = t > 0.f ? t : 0.f;
    t = (v.y + xa.y*es)/dd + b1[4*q+1]; hbuf[4*q+1] = t > 0.f ? t : 0.f;
    t = (v.z + xb.x*es)/dd + b1[4*q+2]; hbuf[4*q+2] = t > 0.f ? t : 0.f;
    t = (v.w + xb.y*es)/dd + b1[4*q+3]; hbuf[4*q+3] = t > 0.f ? t : 0.f;
  }
  float o[14];
#pragma unroll
  for (int j = 0; j < 14; ++j) o[j] = 0.f;
#pragma unroll
  for (int ch = 0; ch < 32; ++ch) {
#pragma unroll
    for (int j = 0; j < 14; ++j)
      o[j] = fmaf(hbuf[ch], w2[14*ch + j], o[j]);
  }
  float s0=0.f, s1=0.f, d0=0.f, d1=0.f;
#pragma unroll
  for (int k = 0; k < 7; ++k) {
    s0 = fmaf(o[k],   atts[k],   s0);
    d0 = fmaf(o[k],   attd[k],   d0);
    s1 = fmaf(o[7+k], atts[7+k], s1);
    d1 = fmaf(o[7+k], attd[7+k], d1);
  }
  // padded fp16 row: head0 -> slots 0..6 (+pad 7), head1 -> slots 8..14 (+pad 15)
  __half2* xo = xlh2 + (size_t)i*8;
#pragma unroll
  for (int q = 0; q < 8; ++q) {
    int p0 = 2*q, p1 = 2*q+1;
    float v0 = ((p0 & 7) < 7) ? o[(p0 >> 3)*7 + (p0 & 7)] : 0.f;
    float v1 = ((p1 & 7) < 7) ? o[(p1 >> 3)*7 + (p1 & 7)] : 0.f;
    xo[q] = __floats2half2_rn(v0, v1);
  }
  as2[2*i] = s0; as2[2*i+1] = s1;
  ad2[2*i] = d0; ad2[2*i+1] = d1;
}

// ---------------- L2 finalize (+self-loop): head-mean + bias + log_softmax -
__global__ void k_final(const float* __restrict__ num2p, // [N,16] padded
                        const float* __restrict__ den2,  // [N,2]
                        const __half2* __restrict__ xlh2,// [N,8] padded
                        const float* __restrict__ as2,   // [N,2]
                        const float* __restrict__ ad2,   // [N,2]
                        const float* __restrict__ b2,    // [7]
                        float* __restrict__ out,         // [N,7]
                        int n) {
  int i = blockIdx.x * blockDim.x + threadIdx.x;
  if (i >= n) return;
  float a0 = as2[2*i]   + ad2[2*i];
  float a1 = as2[2*i+1] + ad2[2*i+1];
  a0 = (a0 >= 0.f) ? a0 : NEG_SLOPE * a0;
  a1 = (a1 >= 0.f) ? a1 : NEG_SLOPE * a1;
  float e0 = __expf(a0), e1 = __expf(a1);
  float d0 = den2[2*i]   + e0 + 1e-16f;
  float d1 = den2[2*i+1] + e1 + 1e-16f;
  const float* nr = num2p + (size_t)i*16;
  const __half2* xr = xlh2 + (size_t)i*8;
  float xf[16];
#pragma unroll
  for (int q = 0; q < 8; ++q) {
    float2 f = __half22float2(xr[q]);
    xf[2*q] = f.x; xf[2*q+1] = f.y;
  }
  float v[7];
#pragma unroll
  for (int c = 0; c < 7; ++c)
    v[c] = 0.5f*((nr[c] + xf[c]*e0)/d0 + (nr[8+c] + xf[8+c]*e1)/d1) + b2[c];
  float m = v[0];
#pragma unroll
  for (int c = 1; c < 7; ++c) m = fmaxf(m, v[c]);
  float s = 0.f;
#pragma unroll
  for (int c = 0; c < 7; ++c) s += __expf(v[c]-m);
  float ls = __logf(s);
#pragma unroll
  for (int c = 0; c < 7; ++c) out[(size_t)i*7+c] = v[c]-m-ls;
}

extern "C" void kernel_launch(void* const* d_in, const int* in_sizes, int n_in,
                              void* d_out, int out_size, void* d_ws, size_t ws_size,
                              hipStream_t stream) {
  const float* x    = (const float*)d_in[0];
  const int*   ei   = (const int*)  d_in[1];
  const float* w1   = (const float*)d_in[2];
  const float* as1w = (const float*)d_in[3];
  const float* ad1w = (const float*)d_in[4];
  const float* b1   = (const float*)d_in[5];
  const float* w2   = (const float*)d_in[6];
  const float* as2w = (const float*)d_in[7];
  const float* ad2w = (const float*)d_in[8];
  const float* b2   = (const float*)d_in[9];
  float* out = (float*)d_out;

  const int n = in_sizes[0] / 3;
  const int E = in_sizes[1] / 2;
  const int* esrc = ei;
  const int* edst = ei + E;
  const int nb = (n + BNODES - 1) >> BUCKET_BITS;   // 782 for n=100000

  const size_t N = (size_t)n;
  float* ws = (float*)d_ws;
  // workspace layout (4-byte units):
  __half2* xlh1 = (__half2*)ws;                    // 16N u32
  float* as1    = ws + 16*N;                       //  2N
  float* ad1    = ws + 18*N;                       //  2N
  __half2* xlh2 = (__half2*)(ws + 20*N);           //  8N u32
  float* as2    = ws + 28*N;                       //  2N
  float* ad2    = ws + 30*N;                       //  2N
  float* num1   = ws + 32*N;                       // 32N
  float* den1   = ws + 64*N;                       //  2N
  float* num2p  = ws + 66*N;                       // 16N
  float* den2   = ws + 82*N;                       //  2N
  // packed aliases num1.. (dead before gather1 writes num1); needs E <= 52N
  unsigned* packed = (unsigned*)num1;
  unsigned* gcount = (unsigned*)(ws + 84*N);       // MAXNB+1
  unsigned* bstart = gcount + (MAXNB + 1);         // MAXNB+1
  unsigned* bcur   = bstart + (MAXNB + 1);         // MAXNB+1
  int*      col    = (int*)(bcur + (MAXNB + 1));   // E
  unsigned* rp     = (unsigned*)(col + E);         // N

  const int nbN = (n + 255) / 256;
  const int nbP = (E + PART_CHUNK - 1) / PART_CHUNK;

  hipMemsetAsync(gcount, 0, (nb + 1) * sizeof(unsigned), stream);

  k_node1<<<nbN, 256, 0, stream>>>(x, w1, as1w, ad1w, xlh1, as1, ad1, n);

  // two-level CSR build (shared by both layers)
  k_hist <<<1024, 256, 0, stream>>>(edst, gcount, E, nb);
  k_scanb<<<1, MAXNB, 0, stream>>>(gcount, bstart, bcur, nb);
  k_part <<<nbP, 256, 0, stream>>>(esrc, edst, bcur, packed, E, nb);
  k_sortb<<<nb, 256, 0, stream>>>(bstart, packed, col, rp, n);

  // Layer 1: 16 lanes per node, 2 channels/lane
  k_gather<8,16><<<(n*16 + 255)/256, 256, 0, stream>>>(
      rp, col, xlh1, as1, ad1, (float2*)num1, den1, n, E);
  k_node2<<<nbN, 256, 0, stream>>>(num1, den1, xlh1, as1, ad1, b1, w2,
                                   as2w, ad2w, xlh2, as2, ad2, n);

  // Layer 2: 8 lanes per node, 2 channels/lane (padded to 8/head)
  k_gather<4,8><<<(n*8 + 255)/256, 256, 0, stream>>>(
      rp, col, xlh2, as2, ad2, (float2*)num2p, den2, n, E);
  k_final<<<nbN, 256, 0, stream>>>(num2p, den2, xlh2, as2, ad2, b2, out, n);
}

// Round 6
// 212.412 us; speedup vs baseline: 5.8960x; 1.1372x over previous
//
#include <hip/hip_runtime.h>
#include <hip/hip_fp16.h>

static constexpr float NEG_SLOPE = 0.2f;
#define BUCKET_BITS 7
#define BNODES (1 << BUCKET_BITS)      // 128 nodes per bucket
#define MAXNB 1024                     // supports n <= 131072 (src fits 17 bits)
#define MAXSUP 32                      // super-buckets (dst >> 12)
#define SUPER_SHIFT 12
#define CHUNK 8192
#define PTHREADS 512
#define SORT_CAP 6144                  // bucket-edge LDS staging capacity

// ---------------- Layer-1 node transform: xl1(fp16) = x@W1, a_src/a_dst ----
__global__ void k_node1(const float* __restrict__ x,
                        const float* __restrict__ w1,    // [3,32]
                        const float* __restrict__ atts,  // [2,16]
                        const float* __restrict__ attd,  // [2,16]
                        __half2* __restrict__ xlh,       // [N,16] half2
                        float* __restrict__ as_,         // [N,2]
                        float* __restrict__ ad_,         // [N,2]
                        int n) {
  int i = blockIdx.x * blockDim.x + threadIdx.x;
  if (i >= n) return;
  float x0 = x[3*i], x1 = x[3*i+1], x2 = x[3*i+2];
  float v[32];
#pragma unroll
  for (int j = 0; j < 32; ++j)
    v[j] = fmaf(x0, w1[j], fmaf(x1, w1[32+j], x2 * w1[64+j]));
  float s0=0.f, s1=0.f, d0=0.f, d1=0.f;
#pragma unroll
  for (int k = 0; k < 16; ++k) {
    s0 = fmaf(v[k],    atts[k],    s0);
    d0 = fmaf(v[k],    attd[k],    d0);
    s1 = fmaf(v[16+k], atts[16+k], s1);
    d1 = fmaf(v[16+k], attd[16+k], d1);
  }
  __half2* o = xlh + (size_t)i*16;
#pragma unroll
  for (int q = 0; q < 16; ++q)
    o[q] = __floats2half2_rn(v[2*q], v[2*q+1]);
  as_[2*i] = s0; as_[2*i+1] = s1;
  ad_[2*i] = d0; ad_[2*i+1] = d1;
}

// ---------------- Super-bucket histogram (32 bins) --------------------------
__global__ void k_hist32(const int* __restrict__ edst, unsigned* __restrict__ scnt,
                         int E) {
  __shared__ unsigned h[MAXSUP];
  if (threadIdx.x < MAXSUP) h[threadIdx.x] = 0u;
  __syncthreads();
  int stride = gridDim.x * blockDim.x;
  for (int e = blockIdx.x * blockDim.x + threadIdx.x; e < E; e += stride)
    atomicAdd(&h[((unsigned)edst[e]) >> SUPER_SHIFT], 1u);
  __syncthreads();
  if (threadIdx.x < MAXSUP && h[threadIdx.x])
    atomicAdd(&scnt[threadIdx.x], h[threadIdx.x]);
}

// ---------------- Exclusive scan over 32 supers (1 thread) -----------------
__global__ void k_scans(const unsigned* __restrict__ scnt,
                        unsigned* __restrict__ sstart, unsigned* __restrict__ scur) {
  if (threadIdx.x == 0) {
    unsigned run = 0;
    for (int s = 0; s < MAXSUP; ++s) { sstart[s] = run; scur[s] = run; run += scnt[s]; }
    sstart[MAXSUP] = run;
  }
}

// ---------------- Pass 1: distribute edges by super (25-32 bins) -----------
// tmp1[slot] = (b_lo<<24) | (dst_local7<<17) | src ; also accumulates gcount.
__global__ void k_part1(const int* __restrict__ esrc, const int* __restrict__ edst,
                        unsigned* __restrict__ scur, unsigned* __restrict__ gcount,
                        unsigned* __restrict__ tmp1, int E) {
  __shared__ unsigned bhist[MAXNB];
  __shared__ unsigned sbase[MAXSUP], soffs[MAXSUP];
  int t = threadIdx.x;
  for (int i = t; i < MAXNB; i += PTHREADS) bhist[i] = 0u;
  if (t < MAXSUP) soffs[t] = 0u;
  __syncthreads();
  int e0 = blockIdx.x * CHUNK;
  int e1 = min(E, e0 + CHUNK);
  for (int e = e0 + t; e < e1; e += PTHREADS)
    atomicAdd(&bhist[((unsigned)edst[e]) >> BUCKET_BITS], 1u);
  __syncthreads();
  if (t < MAXSUP) {                       // super totals = sum of 32 bucket bins
    unsigned v = 0;
#pragma unroll 8
    for (int k = 0; k < 32; ++k) v += bhist[(t << 5) + k];
    sbase[t] = v ? atomicAdd(&scur[t], v) : 0u;
  }
  for (int i = t; i < MAXNB; i += PTHREADS)
    if (bhist[i]) atomicAdd(&gcount[i], bhist[i]);
  __syncthreads();
  for (int e = e0 + t; e < e1; e += PTHREADS) {
    unsigned d = (unsigned)edst[e];
    unsigned hi = d >> SUPER_SHIFT;
    unsigned pk = (((d >> BUCKET_BITS) & 31u) << 24)
                | ((d & (BNODES - 1u)) << 17) | (unsigned)esrc[e];
    unsigned r = atomicAdd(&soffs[hi], 1u);
    tmp1[sbase[hi] + r] = pk;
  }
}

// ---------------- Exclusive scan over buckets (1 block) --------------------
__global__ void k_scanb(const unsigned* __restrict__ gcount,
                        unsigned* __restrict__ start, unsigned* __restrict__ cursor,
                        int nb) {
  __shared__ unsigned sm[MAXNB];
  int t = threadIdx.x;
  unsigned v = (t < nb) ? gcount[t] : 0u;
  sm[t] = v; __syncthreads();
  for (int off = 1; off < MAXNB; off <<= 1) {
    unsigned u = (t >= off) ? sm[t - off] : 0u;
    __syncthreads();
    sm[t] += u;
    __syncthreads();
  }
  if (t < nb) { unsigned excl = sm[t] - v; start[t] = excl; cursor[t] = excl; }
  if (t == nb - 1) start[nb] = sm[t];   // total = E
}

// ---------------- Pass 2: within super, distribute by b_lo (32 bins) -------
__global__ void k_part2(const unsigned* __restrict__ tmp1,
                        const unsigned* __restrict__ sstart, // [MAXSUP+1]
                        unsigned* __restrict__ bcur,
                        unsigned* __restrict__ packed2,
                        int E, int nb) {
  __shared__ unsigned stage[CHUNK];
  __shared__ unsigned sst[MAXSUP + 1];
  __shared__ unsigned hist[4*32], base[4*32], offs[4*32];
  __shared__ int s0sh;
  int t = threadIdx.x;
  if (t <= MAXSUP) sst[t] = sstart[t];
  if (t < 128) { hist[t] = 0u; offs[t] = 0u; }
  __syncthreads();
  int e0 = blockIdx.x * CHUNK;
  int e1 = min(E, e0 + CHUNK);
  if (t == 0) {
    int s = 0;
    while (s + 1 < MAXSUP && (int)sst[s + 1] <= e0) ++s;
    s0sh = s;
  }
  __syncthreads();
  int s0 = s0sh;
  {   // count phase (+ stash ds in bits 29..31)
    int s = s0;
    for (int e = e0 + t; e < e1; e += PTHREADS) {
      while ((unsigned)e >= sst[s + 1]) ++s;
      unsigned pk = tmp1[e];
      int ds = s - s0;
      if (ds < 4) {
        atomicAdd(&hist[(ds << 5) | (pk >> 24)], 1u);
        stage[e - e0] = pk | ((unsigned)ds << 29);
      } else {                            // rare straddle fallback
        unsigned b = ((unsigned)s << 5) | (pk >> 24);
        unsigned slot = atomicAdd(&bcur[b], 1u);
        packed2[slot] = pk & 0x00FFFFFFu;
        stage[e - e0] = 0xFFFFFFFFu;      // ds==7 sentinel
      }
    }
  }
  __syncthreads();
  if (t < 128) {
    unsigned b = (((unsigned)(s0 + (t >> 5))) << 5) | (t & 31u);
    if (hist[t] && b < (unsigned)nb)
      base[t] = atomicAdd(&bcur[b], hist[t]);
  }
  __syncthreads();
  for (int e = e0 + t; e < e1; e += PTHREADS) {
    unsigned v = stage[e - e0];
    unsigned ds = v >> 29;
    if (ds < 4u) {
      unsigned idx = (ds << 5) | ((v >> 24) & 31u);
      unsigned r = atomicAdd(&offs[idx], 1u);
      packed2[base[idx] + r] = v & 0x00FFFFFFu;
    }
  }
}

// ---------------- Per-bucket LDS sort: bucket run -> node-sorted col + rp --
__global__ void k_sortb(const unsigned* __restrict__ bstart,
                        const unsigned* __restrict__ packed,
                        int* __restrict__ col,
                        unsigned* __restrict__ rp,
                        int n) {
  __shared__ unsigned stage_in[SORT_CAP];
  __shared__ unsigned stage_out[SORT_CAP];
  __shared__ unsigned cnt[BNODES], excl[BNODES], off[BNODES];
  int b = blockIdx.x;
  unsigned s0 = bstart[b], s1 = bstart[b + 1];
  int size = (int)(s1 - s0);
  int t = threadIdx.x;
  if (t < BNODES) cnt[t] = 0u;
  __syncthreads();
  bool lds_path = (size <= SORT_CAP);
  if (lds_path) {
    for (int i = t; i < size; i += blockDim.x) {
      unsigned pk = packed[s0 + i];
      stage_in[i] = pk;
      atomicAdd(&cnt[pk >> 17], 1u);
    }
  } else {
    for (int i = t; i < size; i += blockDim.x)
      atomicAdd(&cnt[packed[s0 + i] >> 17], 1u);
  }
  __syncthreads();
  if (t == 0) {
    unsigned run = 0;
#pragma unroll 4
    for (int i = 0; i < BNODES; ++i) { excl[i] = run; run += cnt[i]; }
  }
  __syncthreads();
  if (t < BNODES) off[t] = excl[t];
  __syncthreads();
  if (lds_path) {
    for (int i = t; i < size; i += blockDim.x) {
      unsigned pk = stage_in[i];
      unsigned slot = atomicAdd(&off[pk >> 17], 1u);
      stage_out[slot] = pk & 0x1FFFFu;
    }
    __syncthreads();
    for (int i = t; i < size; i += blockDim.x)
      col[s0 + i] = (int)stage_out[i];
  } else {
    for (int i = t; i < size; i += blockDim.x) {
      unsigned pk = packed[s0 + i];
      unsigned slot = atomicAdd(&off[pk >> 17], 1u);
      col[s0 + slot] = (int)(pk & 0x1FFFFu);
    }
  }
  int base = b << BUCKET_BITS;
  if (t < BNODES && base + t < n) rp[base + t] = s0 + excl[t];
}

// ---------------- Gather edge pass: LPE lanes/node, 2 ch/lane, unroll 4 ----
template<int PPH, int LPE>
__global__ void k_gather(const unsigned* __restrict__ rp,
                         const int* __restrict__ col,
                         const __half2* __restrict__ xlh, // [N,LPE] half2
                         const float* __restrict__ as_,   // [N,2]
                         const float* __restrict__ ad_,   // [N,2]
                         float2* __restrict__ num,        // [N,LPE] float2
                         float* __restrict__ den,         // [N,2]
                         int n, int E) {
  int d = blockIdx.x * (blockDim.x / LPE) + threadIdx.x / LPE;
  int lane = threadIdx.x & (LPE - 1);
  if (d >= n) return;
  int h = lane / PPH;
  float adh = ad_[2*d + h];
  float acc0 = 0.f, acc1 = 0.f, dsum = 0.f;
  unsigned jb = rp[d];
  unsigned je = (d + 1 < n) ? rp[d + 1] : (unsigned)E;
  unsigned j = jb;
  for (; j + 4 <= je; j += 4) {
    int s0 = col[j], s1 = col[j+1], s2 = col[j+2], s3 = col[j+3];
    float b0 = as_[2*s0 + h], b1 = as_[2*s1 + h],
          b2 = as_[2*s2 + h], b3 = as_[2*s3 + h];
    __half2 x0 = xlh[(size_t)s0*LPE + lane];
    __half2 x1 = xlh[(size_t)s1*LPE + lane];
    __half2 x2 = xlh[(size_t)s2*LPE + lane];
    __half2 x3 = xlh[(size_t)s3*LPE + lane];
    float a;
    a = b0 + adh; a = (a >= 0.f) ? a : NEG_SLOPE*a; float e0 = __expf(a);
    a = b1 + adh; a = (a >= 0.f) ? a : NEG_SLOPE*a; float e1 = __expf(a);
    a = b2 + adh; a = (a >= 0.f) ? a : NEG_SLOPE*a; float e2 = __expf(a);
    a = b3 + adh; a = (a >= 0.f) ? a : NEG_SLOPE*a; float e3 = __expf(a);
    float2 f;
    f = __half22float2(x0); acc0 = fmaf(f.x, e0, acc0); acc1 = fmaf(f.y, e0, acc1);
    f = __half22float2(x1); acc0 = fmaf(f.x, e1, acc0); acc1 = fmaf(f.y, e1, acc1);
    f = __half22float2(x2); acc0 = fmaf(f.x, e2, acc0); acc1 = fmaf(f.y, e2, acc1);
    f = __half22float2(x3); acc0 = fmaf(f.x, e3, acc0); acc1 = fmaf(f.y, e3, acc1);
    dsum += (e0 + e1) + (e2 + e3);
  }
  for (; j < je; ++j) {
    int s = col[j];
    float a = as_[2*s + h] + adh;
    a = (a >= 0.f) ? a : NEG_SLOPE*a;
    float ee = __expf(a);
    float2 f = __half22float2(xlh[(size_t)s*LPE + lane]);
    acc0 = fmaf(f.x, ee, acc0); acc1 = fmaf(f.y, ee, acc1);
    dsum += ee;
  }
  num[(size_t)d*LPE + lane] = make_float2(acc0, acc1);
  if ((lane & (PPH - 1)) == 0) den[2*d + h] = dsum;
}

// ---------------- L1 finalize (+self-loop) + ReLU + L2 transform -----------
__global__ void k_node2(const float* __restrict__ num1,  // [N,32]
                        const float* __restrict__ den1,  // [N,2]
                        const __half2* __restrict__ xlh1,// [N,16]
                        const float* __restrict__ as1,   // [N,2]
                        const float* __restrict__ ad1,   // [N,2]
                        const float* __restrict__ b1,    // [32]
                        const float* __restrict__ w2,    // [32,14]
                        const float* __restrict__ atts,  // [2,7]
                        const float* __restrict__ attd,  // [2,7]
                        __half2* __restrict__ xlh2,      // [N,8] padded (8/head)
                        float* __restrict__ as2,         // [N,2]
                        float* __restrict__ ad2,         // [N,2]
                        int n) {
  int i = blockIdx.x * blockDim.x + threadIdx.x;
  if (i >= n) return;
  float a0 = as1[2*i]   + ad1[2*i];
  float a1 = as1[2*i+1] + ad1[2*i+1];
  a0 = (a0 >= 0.f) ? a0 : NEG_SLOPE * a0;
  a1 = (a1 >= 0.f) ? a1 : NEG_SLOPE * a1;
  float e0 = __expf(a0), e1 = __expf(a1);
  float dh0 = den1[2*i]   + e0 + 1e-16f;
  float dh1 = den1[2*i+1] + e1 + 1e-16f;
  const float4* nr = reinterpret_cast<const float4*>(num1 + (size_t)i*32);
  const __half2* xr = xlh1 + (size_t)i*16;
  float hbuf[32];
#pragma unroll
  for (int q = 0; q < 8; ++q) {
    float4 v = nr[q];
    float2 xa = __half22float2(xr[2*q]);
    float2 xb = __half22float2(xr[2*q+1]);
    float es = (q < 4) ? e0 : e1;
    float dd = (q < 4) ? dh0 : dh1;
    float t;
    t = (v.x + xa.x*es)/dd + b1[4*q];   hbuf[4*q]   = t > 0.f ? t : 0.f;
    t = (v.y + xa.y*es)/dd + b1[4*q+1]; hbuf[4*q+1] = t > 0.f ? t : 0.f;
    t = (v.z + xb.x*es)/dd + b1[4*q+2]; hbuf[4*q+2] = t > 0.f ? t : 0.f;
    t = (v.w + xb.y*es)/dd + b1[4*q+3]; hbuf[4*q+3] = t > 0.f ? t : 0.f;
  }
  float o[14];
#pragma unroll
  for (int j = 0; j < 14; ++j) o[j] = 0.f;
#pragma unroll
  for (int ch = 0; ch < 32; ++ch) {
#pragma unroll
    for (int j = 0; j < 14; ++j)
      o[j] = fmaf(hbuf[ch], w2[14*ch + j], o[j]);
  }
  float s0=0.f, s1=0.f, d0=0.f, d1=0.f;
#pragma unroll
  for (int k = 0; k < 7; ++k) {
    s0 = fmaf(o[k],   atts[k],   s0);
    d0 = fmaf(o[k],   attd[k],   d0);
    s1 = fmaf(o[7+k], atts[7+k], s1);
    d1 = fmaf(o[7+k], attd[7+k], d1);
  }
  __half2* xo = xlh2 + (size_t)i*8;
#pragma unroll
  for (int q = 0; q < 8; ++q) {
    int p0 = 2*q, p1 = 2*q+1;
    float v0 = ((p0 & 7) < 7) ? o[(p0 >> 3)*7 + (p0 & 7)] : 0.f;
    float v1 = ((p1 & 7) < 7) ? o[(p1 >> 3)*7 + (p1 & 7)] : 0.f;
    xo[q] = __floats2half2_rn(v0, v1);
  }
  as2[2*i] = s0; as2[2*i+1] = s1;
  ad2[2*i] = d0; ad2[2*i+1] = d1;
}

// ---------------- L2 finalize (+self-loop): head-mean + bias + log_softmax -
__global__ void k_final(const float* __restrict__ num2p, // [N,16] padded
                        const float* __restrict__ den2,  // [N,2]
                        const __half2* __restrict__ xlh2,// [N,8] padded
                        const float* __restrict__ as2,   // [N,2]
                        const float* __restrict__ ad2,   // [N,2]
                        const float* __restrict__ b2,    // [7]
                        float* __restrict__ out,         // [N,7]
                        int n) {
  int i = blockIdx.x * blockDim.x + threadIdx.x;
  if (i >= n) return;
  float a0 = as2[2*i]   + ad2[2*i];
  float a1 = as2[2*i+1] + ad2[2*i+1];
  a0 = (a0 >= 0.f) ? a0 : NEG_SLOPE * a0;
  a1 = (a1 >= 0.f) ? a1 : NEG_SLOPE * a1;
  float e0 = __expf(a0), e1 = __expf(a1);
  float d0 = den2[2*i]   + e0 + 1e-16f;
  float d1 = den2[2*i+1] + e1 + 1e-16f;
  const float* nr = num2p + (size_t)i*16;
  const __half2* xr = xlh2 + (size_t)i*8;
  float xf[16];
#pragma unroll
  for (int q = 0; q < 8; ++q) {
    float2 f = __half22float2(xr[q]);
    xf[2*q] = f.x; xf[2*q+1] = f.y;
  }
  float v[7];
#pragma unroll
  for (int c = 0; c < 7; ++c)
    v[c] = 0.5f*((nr[c] + xf[c]*e0)/d0 + (nr[8+c] + xf[8+c]*e1)/d1) + b2[c];
  float m = v[0];
#pragma unroll
  for (int c = 1; c < 7; ++c) m = fmaxf(m, v[c]);
  float s = 0.f;
#pragma unroll
  for (int c = 0; c < 7; ++c) s += __expf(v[c]-m);
  float ls = __logf(s);
#pragma unroll
  for (int c = 0; c < 7; ++c) out[(size_t)i*7+c] = v[c]-m-ls;
}

extern "C" void kernel_launch(void* const* d_in, const int* in_sizes, int n_in,
                              void* d_out, int out_size, void* d_ws, size_t ws_size,
                              hipStream_t stream) {
  const float* x    = (const float*)d_in[0];
  const int*   ei   = (const int*)  d_in[1];
  const float* w1   = (const float*)d_in[2];
  const float* as1w = (const float*)d_in[3];
  const float* ad1w = (const float*)d_in[4];
  const float* b1   = (const float*)d_in[5];
  const float* w2   = (const float*)d_in[6];
  const float* as2w = (const float*)d_in[7];
  const float* ad2w = (const float*)d_in[8];
  const float* b2   = (const float*)d_in[9];
  float* out = (float*)d_out;

  const int n = in_sizes[0] / 3;
  const int E = in_sizes[1] / 2;
  const int* esrc = ei;
  const int* edst = ei + E;
  const int nb = (n + BNODES - 1) >> BUCKET_BITS;   // 782 for n=100000

  const size_t N = (size_t)n;
  float* ws = (float*)d_ws;
  // workspace layout (4-byte units):
  __half2* xlh1 = (__half2*)ws;                    // 16N
  float* as1    = ws + 16*N;                       //  2N
  float* ad1    = ws + 18*N;                       //  2N
  __half2* xlh2 = (__half2*)(ws + 20*N);           //  8N
  float* as2    = ws + 28*N;                       //  2N
  float* ad2    = ws + 30*N;                       //  2N
  float* num1   = ws + 32*N;                       // 32N
  float* den1   = ws + 64*N;                       //  2N
  float* num2p  = ws + 66*N;                       // 16N
  float* den2   = ws + 82*N;                       //  2N -> 84N
  unsigned* ctrl   = (unsigned*)(ws + 84*N);
  unsigned* scnt   = ctrl;                         // 32
  unsigned* scur   = ctrl + 32;                    // 32
  unsigned* sstart = ctrl + 64;                    // 33
  unsigned* gcount = ctrl + 97;                    // MAXNB+1
  unsigned* bstart = ctrl + 97 + (MAXNB + 1);      // MAXNB+1
  unsigned* bcur   = ctrl + 97 + 2*(MAXNB + 1);    // MAXNB+1
  unsigned* rp     = ctrl + 97 + 3*(MAXNB + 1);    // N
  int*      col    = (int*)(rp + N);               // E
  unsigned* packed2= (unsigned*)(col + E);         // E
  unsigned* tmp1   = (unsigned*)num1;              // E (alias; E <= 32N here)

  const int nbN = (n + 255) / 256;
  const int nbC = (E + CHUNK - 1) / CHUNK;

  // zero scnt + scur + sstart + gcount (first 97 + MAXNB+1 words)
  hipMemsetAsync(ctrl, 0, (97 + MAXNB + 1) * sizeof(unsigned), stream);

  k_node1<<<nbN, 256, 0, stream>>>(x, w1, as1w, ad1w, xlh1, as1, ad1, n);

  // two-level radix CSR build (shared by both layers)
  k_hist32<<<512, 256, 0, stream>>>(edst, scnt, E);
  k_scans <<<1, 64, 0, stream>>>(scnt, sstart, scur);
  k_part1 <<<nbC, PTHREADS, 0, stream>>>(esrc, edst, scur, gcount, tmp1, E);
  k_scanb <<<1, MAXNB, 0, stream>>>(gcount, bstart, bcur, nb);
  k_part2 <<<nbC, PTHREADS, 0, stream>>>(tmp1, sstart, bcur, packed2, E, nb);
  k_sortb <<<nb, 256, 0, stream>>>(bstart, packed2, col, rp, n);

  // Layer 1: 16 lanes per node, 2 channels/lane (tmp1/num1 now reusable)
  k_gather<8,16><<<(n*16 + 255)/256, 256, 0, stream>>>(
      rp, col, xlh1, as1, ad1, (float2*)num1, den1, n, E);
  k_node2<<<nbN, 256, 0, stream>>>(num1, den1, xlh1, as1, ad1, b1, w2,
                                   as2w, ad2w, xlh2, as2, ad2, n);

  // Layer 2: 8 lanes per node, 2 channels/lane (padded to 8/head)
  k_gather<4,8><<<(n*8 + 255)/256, 256, 0, stream>>>(
      rp, col, xlh2, as2, ad2, (float2*)num2p, den2, n, E);
  k_final<<<nbN, 256, 0, stream>>>(num2p, den2, xlh2, as2, ad2, b2, out, n);
}